// Round 1
// baseline (252.119 us; speedup 1.0000x reference)
//
#include <hip/hip_runtime.h>
#include <hip/hip_bf16.h>

// Problem constants (from setup_inputs)
#define B_ROWS 4096
#define D_IN   512
#define D_PCA  100
#define KP     128            // padded K (100 data + 4 aug + 24 zero)
#define N_REF  50000
#define N_PAD  50048          // 391 * 128
#define NCH    391            // chunks of 128 X-rows
#define NSPLIT 32

typedef __attribute__((ext_vector_type(8))) short s8v;   // 8 x bf16 (4 VGPR)
typedef __attribute__((ext_vector_type(4))) float f4v;   // 4 x f32

// ---------------- Kernel A: PCA projection + augmentation ----------------
// h'[b] = [bf16(h_0..99), hi(-0.5|h|^2), lo(-0.5|h|^2), 1, 1, 0...0]
__global__ __launch_bounds__(256) void pca_kernel(
    const float* __restrict__ x, const float* __restrict__ W,
    const float* __restrict__ bvec, __hip_bfloat16* __restrict__ Hb) {
  __shared__ float xs[16][516];   // +4 pad breaks LDS bank aliasing
  __shared__ float hl[16][104];
  __shared__ float ahi[16], alo[16];
  const int t = threadIdx.x;
  const int blk = blockIdx.x;
  const float4* xsrc = (const float4*)(x + (size_t)blk * 16 * 512);
  for (int i = t; i < 2048; i += 256) {          // 16 rows x 512 f32, vectorized
    float4 v = xsrc[i];
    int r = i >> 7, c4 = (i & 127) * 4;
    xs[r][c4] = v.x; xs[r][c4 + 1] = v.y; xs[r][c4 + 2] = v.z; xs[r][c4 + 3] = v.w;
  }
  __syncthreads();
  const int r = t & 15, cb = t >> 4;             // 16 rows x 16 col-groups
  for (int pass = 0; pass < 7; ++pass) {
    const int c = cb + pass * 16;
    if (c < D_PCA) {
      const float4* Wv = (const float4*)(W + (size_t)c * 512);
      const float4* xv = (const float4*)(&xs[r][0]);
      float a0 = 0.f, a1 = 0.f, a2 = 0.f, a3 = 0.f;
      for (int k4 = 0; k4 < 128; ++k4) {
        float4 xx = xv[k4]; float4 ww = Wv[k4];
        a0 = fmaf(xx.x, ww.x, a0); a1 = fmaf(xx.y, ww.y, a1);
        a2 = fmaf(xx.z, ww.z, a2); a3 = fmaf(xx.w, ww.w, a3);
      }
      hl[r][c] = (a0 + a1) + (a2 + a3) + bvec[c];
    }
  }
  __syncthreads();
  if (t < 16) {
    float s = 0.f;
    for (int c = 0; c < D_PCA; ++c) { float v = hl[t][c]; s = fmaf(v, v, s); }
    float v = -0.5f * s;
    float hi = __bfloat162float(__float2bfloat16(v));
    ahi[t] = hi; alo[t] = v - hi;
  }
  __syncthreads();
  for (int o = t; o < 16 * KP; o += 256) {
    const int rr = o >> 7, c = o & 127;
    float val;
    if (c < D_PCA) val = hl[rr][c];
    else if (c == 100) val = ahi[rr];
    else if (c == 101) val = alo[rr];
    else if (c == 102 || c == 103) val = 1.0f;
    else val = 0.0f;
    Hb[(size_t)(blk * 16 + rr) * KP + c] = __float2bfloat16(val);
  }
}

// ---------------- Kernel B: X_ref augmentation ----------------
// X'[n] = [bf16(X_0..99), 1, 1, hi(-0.5|X|^2), lo(-0.5|X|^2), 0...0]
// pad rows (n >= N): all zero except col102 = -30000 (=> logit -> -inf)
__global__ __launch_bounds__(256) void xprep_kernel(
    const float* __restrict__ X, __hip_bfloat16* __restrict__ Xb) {
  __shared__ float xl[1600];
  __shared__ float bhi[16], blo[16];
  const int t = threadIdx.x;
  const long n0 = (long)blockIdx.x * 16;
  if (n0 < N_REF) {
    const float4* src = (const float4*)(X + n0 * D_PCA);
    for (int i = t; i < 400; i += 256) ((float4*)xl)[i] = src[i];
    __syncthreads();
    if (t < 16) {
      float s = 0.f;
      for (int c = 0; c < D_PCA; ++c) { float v = xl[t * 100 + c]; s = fmaf(v, v, s); }
      float v = -0.5f * s;
      float hi = __bfloat162float(__float2bfloat16(v));
      bhi[t] = hi; blo[t] = v - hi;
    }
    __syncthreads();
    for (int o = t; o < 2048; o += 256) {
      const int r = o >> 7, c = o & 127;
      float val;
      if (c < D_PCA) val = xl[r * 100 + c];
      else if (c == 100 || c == 101) val = 1.0f;
      else if (c == 102) val = bhi[r];
      else if (c == 103) val = blo[r];
      else val = 0.0f;
      Xb[(n0 + r) * KP + c] = __float2bfloat16(val);
    }
  } else {
    for (int o = t; o < 2048; o += 256) {
      const int r = o >> 7, c = o & 127;
      Xb[(n0 + r) * KP + c] = __float2bfloat16(c == 102 ? -30000.0f : 0.0f);
    }
  }
}

// ---------------- Kernel C: fused distance-matmul + exp-sum ----------------
__device__ __forceinline__ void stage_tile(char* lds, const char* gtile, int t) {
#pragma unroll
  for (int i = 0; i < 8; ++i) {
    const int L = i * 4096 + t * 16;                 // linear LDS dest (lane-contiguous)
    const int G = L ^ (((L >> 8) & 7) << 4);         // pre-swizzled global source (involution)
    __builtin_amdgcn_global_load_lds(
        (const __attribute__((address_space(1))) void*)(gtile + G),
        (__attribute__((address_space(3))) void*)(lds + L), 16, 0, 0);
  }
}

__global__ __launch_bounds__(256, 2) void kde_kernel(
    const __hip_bfloat16* __restrict__ Hb, const char* __restrict__ Xbc,
    const float* __restrict__ bwp, float* __restrict__ spart) {
  __shared__ char ldsx[2][32768];                    // double-buffered X' chunk [128][256B]
  const int t = threadIdx.x;
  const int lane = t & 63, w = t >> 6;
  const int g = lane >> 4, l15 = lane & 15;
  const int rb = blockIdx.x / NSPLIT, sp = blockIdx.x % NSPLIT;
  const int c0 = (sp * NCH) / NSPLIT;
  const int c1 = ((sp + 1) * NCH) / NSPLIT;
  const float bw = bwp[0];
  const float k1 = 1.4426950408889634f / (bw * bw);  // log2(e)/bw^2
  const int rowbase = rb * 256 + w * 64;             // 4 waves x 64 rows = 256 rows/block

  // A fragments: h' rows held in registers for the whole kernel (4 rf x 4 ks)
  s8v a[4][4];
#pragma unroll
  for (int rf = 0; rf < 4; ++rf)
#pragma unroll
    for (int ks = 0; ks < 4; ++ks) {
      const int row = rowbase + rf * 16 + l15;
      a[rf][ks] = *(const s8v*)(Hb + (size_t)row * KP + ks * 32 + g * 8);
    }

  float sacc[16];                                    // per-lane partial sums (rf x reg)
#pragma unroll
  for (int i = 0; i < 16; ++i) sacc[i] = 0.0f;

  stage_tile(ldsx[0], Xbc + (size_t)c0 * 32768, t);
  __syncthreads();

  const f4v zero4 = {0.0f, 0.0f, 0.0f, 0.0f};
  for (int ch = c0; ch < c1; ++ch) {
    const int cur = (ch - c0) & 1;
    if (ch + 1 < c1) stage_tile(ldsx[cur ^ 1], Xbc + (size_t)(ch + 1) * 32768, t);
    const char* lx = ldsx[cur];
#pragma unroll
    for (int half = 0; half < 2; ++half) {           // 2 halves of 4 col-frags: caps VGPRs
      f4v acc[4][4];
#pragma unroll
      for (int cf4 = 0; cf4 < 4; ++cf4) {
        const int nl = (half * 4 + cf4) * 16 + l15;  // local X row in chunk
        const int sw = (nl & 7) << 4;                // read-side XOR swizzle
        const int qb = nl * 256 + g * 16;
        s8v b0 = *(const s8v*)(lx + ((qb) ^ sw));
        s8v b1 = *(const s8v*)(lx + ((qb + 64) ^ sw));
        s8v b2 = *(const s8v*)(lx + ((qb + 128) ^ sw));
        s8v b3 = *(const s8v*)(lx + ((qb + 192) ^ sw));
#pragma unroll
        for (int rf = 0; rf < 4; ++rf) {
          f4v a0 = __builtin_amdgcn_mfma_f32_16x16x32_bf16(a[rf][0], b0, zero4, 0, 0, 0);
          a0 = __builtin_amdgcn_mfma_f32_16x16x32_bf16(a[rf][1], b1, a0, 0, 0, 0);
          a0 = __builtin_amdgcn_mfma_f32_16x16x32_bf16(a[rf][2], b2, a0, 0, 0, 0);
          a0 = __builtin_amdgcn_mfma_f32_16x16x32_bf16(a[rf][3], b3, a0, 0, 0, 0);
          acc[rf][cf4] = a0;
        }
      }
      // epilogue: acc = -sqdist/2 (aug trick); s += exp(acc/bw^2 + 100), branch-free
#pragma unroll
      for (int rf = 0; rf < 4; ++rf)
#pragma unroll
        for (int cf4 = 0; cf4 < 4; ++cf4)
#pragma unroll
          for (int reg = 0; reg < 4; ++reg)
            sacc[rf * 4 + reg] += exp2f(fmaf(acc[rf][cf4][reg], k1, 144.26950408889634f));
    }
    __syncthreads();  // drains prefetch vmcnt + guards LDS reuse (single barrier/chunk)
  }

  // butterfly-reduce the 16 column-lanes; rows live at lane-group g, regs rf x reg
#pragma unroll
  for (int i = 0; i < 16; ++i) {
    float v = sacc[i];
    v += __shfl_xor(v, 1, 64);
    v += __shfl_xor(v, 2, 64);
    v += __shfl_xor(v, 4, 64);
    v += __shfl_xor(v, 8, 64);
    sacc[i] = v;
  }
  if (l15 == 0) {
#pragma unroll
    for (int rf = 0; rf < 4; ++rf)
#pragma unroll
      for (int reg = 0; reg < 4; ++reg) {
        const int row = rowbase + rf * 16 + g * 4 + reg;
        spart[sp * B_ROWS + row] = sacc[rf * 4 + reg];
      }
  }
}

// ---------------- Kernel D: combine partials ----------------
__global__ __launch_bounds__(256) void combine_kernel(
    const float* __restrict__ spart, const float* __restrict__ bwp,
    float* __restrict__ out) {
  const int b = blockIdx.x * 256 + threadIdx.x;
  if (b >= B_ROWS) return;
  float s = 0.f;
#pragma unroll
  for (int sp = 0; sp < NSPLIT; ++sp) s += spart[sp * B_ROWS + b];
  const float bw = bwp[0];
  const float LOG2PI = 1.8378770664093453f;
  const float coeff = -logf((float)N_REF) - 0.5f * LOG2PI * (float)D_PCA
                      - logf(bw) * (float)D_PCA;
  out[b] = logf(s) - 100.0f + coeff;   // undo the +100 exp shift
}

// ---------------- Launch ----------------
extern "C" void kernel_launch(void* const* d_in, const int* in_sizes, int n_in,
                              void* d_out, int out_size, void* d_ws, size_t ws_size,
                              hipStream_t stream) {
  const float* x     = (const float*)d_in[0];   // [4096,512]
  const float* W     = (const float*)d_in[1];   // [100,512]
  const float* bvec  = (const float*)d_in[2];   // [100]
  const float* X     = (const float*)d_in[3];   // [50000,100]
  const float* bwp   = (const float*)d_in[4];   // scalar
  float* out = (float*)d_out;

  char* ws = (char*)d_ws;
  __hip_bfloat16* Hb = (__hip_bfloat16*)ws;                       // 4096*128*2  = 1 MiB
  __hip_bfloat16* Xb = (__hip_bfloat16*)(ws + 1048576);           // 50048*128*2 = 12.22 MiB
  float* spart       = (float*)(ws + 1048576 + 12812288);         // 32*4096*4   = 0.5 MiB

  pca_kernel<<<dim3(B_ROWS / 16), dim3(256), 0, stream>>>(x, W, bvec, Hb);
  xprep_kernel<<<dim3(N_PAD / 16), dim3(256), 0, stream>>>(X, Xb);
  kde_kernel<<<dim3((B_ROWS / 256) * NSPLIT), dim3(256), 0, stream>>>(
      Hb, (const char*)Xb, bwp, spart);
  combine_kernel<<<dim3(B_ROWS / 256), dim3(256), 0, stream>>>(spart, bwp, out);
}

// Round 2
// 117.538 us; speedup vs baseline: 2.1450x; 2.1450x over previous
//
#include <hip/hip_runtime.h>
#include <hip/hip_bf16.h>

// Problem constants (from setup_inputs)
#define B_ROWS 4096
#define D_IN   512
#define D_PCA  100
#define KP     128            // padded K (100 data + 4 aug + 24 zero)
#define N_REF  50000
#define N_PAD  50048          // 782 * 64
#define NCH    782            // chunks of 64 X-rows
#define NSPLIT 32
#define CH_BYTES 16384        // 64 rows * 256 B

typedef __attribute__((ext_vector_type(8))) short s8v;   // 8 x bf16 (4 VGPR)
typedef __attribute__((ext_vector_type(4))) float f4v;   // 4 x f32

__device__ __forceinline__ float fast_exp2(float x) {
#if __has_builtin(__builtin_amdgcn_exp2f)
  return __builtin_amdgcn_exp2f(x);
#else
  float r; asm("v_exp_f32 %0, %1" : "=v"(r) : "v"(x)); return r;
#endif
}

// ---------------- Kernel A: PCA projection + augmentation ----------------
// h'[b] = [bf16(h_0..99), hi(-0.5|h|^2), lo(-0.5|h|^2), 1, 1, 0...0]
__global__ __launch_bounds__(256) void pca_kernel(
    const float* __restrict__ x, const float* __restrict__ W,
    const float* __restrict__ bvec, __hip_bfloat16* __restrict__ Hb) {
  __shared__ float xs[16][516];   // +4 pad breaks LDS bank aliasing
  __shared__ float hl[16][104];
  __shared__ float ahi[16], alo[16];
  const int t = threadIdx.x;
  const int blk = blockIdx.x;
  const float4* xsrc = (const float4*)(x + (size_t)blk * 16 * 512);
  for (int i = t; i < 2048; i += 256) {          // 16 rows x 512 f32, vectorized
    float4 v = xsrc[i];
    int r = i >> 7, c4 = (i & 127) * 4;
    xs[r][c4] = v.x; xs[r][c4 + 1] = v.y; xs[r][c4 + 2] = v.z; xs[r][c4 + 3] = v.w;
  }
  __syncthreads();
  const int r = t & 15, cb = t >> 4;             // 16 rows x 16 col-groups
  for (int pass = 0; pass < 7; ++pass) {
    const int c = cb + pass * 16;
    if (c < D_PCA) {
      const float4* Wv = (const float4*)(W + (size_t)c * 512);
      const float4* xv = (const float4*)(&xs[r][0]);
      float a0 = 0.f, a1 = 0.f, a2 = 0.f, a3 = 0.f;
      for (int k4 = 0; k4 < 128; ++k4) {
        float4 xx = xv[k4]; float4 ww = Wv[k4];
        a0 = fmaf(xx.x, ww.x, a0); a1 = fmaf(xx.y, ww.y, a1);
        a2 = fmaf(xx.z, ww.z, a2); a3 = fmaf(xx.w, ww.w, a3);
      }
      hl[r][c] = (a0 + a1) + (a2 + a3) + bvec[c];
    }
  }
  __syncthreads();
  if (t < 16) {
    float s = 0.f;
    for (int c = 0; c < D_PCA; ++c) { float v = hl[t][c]; s = fmaf(v, v, s); }
    float v = -0.5f * s;
    float hi = __bfloat162float(__float2bfloat16(v));
    ahi[t] = hi; alo[t] = v - hi;
  }
  __syncthreads();
  for (int o = t; o < 16 * KP; o += 256) {
    const int rr = o >> 7, c = o & 127;
    float val;
    if (c < D_PCA) val = hl[rr][c];
    else if (c == 100) val = ahi[rr];
    else if (c == 101) val = alo[rr];
    else if (c == 102 || c == 103) val = 1.0f;
    else val = 0.0f;
    Hb[(size_t)(blk * 16 + rr) * KP + c] = __float2bfloat16(val);
  }
}

// ---------------- Kernel B: X_ref augmentation ----------------
// X'[n] = [bf16(X_0..99), 1, 1, hi(-0.5|X|^2), lo(-0.5|X|^2), 0...0]
// pad rows (n >= N): all zero except col102 = -30000 (=> logit -> -inf)
__global__ __launch_bounds__(256) void xprep_kernel(
    const float* __restrict__ X, __hip_bfloat16* __restrict__ Xb) {
  __shared__ float xl[1600];
  __shared__ float bhi[16], blo[16];
  const int t = threadIdx.x;
  const long n0 = (long)blockIdx.x * 16;
  if (n0 < N_REF) {
    const float4* src = (const float4*)(X + n0 * D_PCA);
    for (int i = t; i < 400; i += 256) ((float4*)xl)[i] = src[i];
    __syncthreads();
    if (t < 16) {
      float s = 0.f;
      for (int c = 0; c < D_PCA; ++c) { float v = xl[t * 100 + c]; s = fmaf(v, v, s); }
      float v = -0.5f * s;
      float hi = __bfloat162float(__float2bfloat16(v));
      bhi[t] = hi; blo[t] = v - hi;
    }
    __syncthreads();
    for (int o = t; o < 2048; o += 256) {
      const int r = o >> 7, c = o & 127;
      float val;
      if (c < D_PCA) val = xl[r * 100 + c];
      else if (c == 100 || c == 101) val = 1.0f;
      else if (c == 102) val = bhi[r];
      else if (c == 103) val = blo[r];
      else val = 0.0f;
      Xb[(n0 + r) * KP + c] = __float2bfloat16(val);
    }
  } else {
    for (int o = t; o < 2048; o += 256) {
      const int r = o >> 7, c = o & 127;
      Xb[(n0 + r) * KP + c] = __float2bfloat16(c == 102 ? -30000.0f : 0.0f);
    }
  }
}

// ---------------- Kernel C: fused distance-matmul + exp-sum ----------------
// stage one 64-row X' chunk (16 KB): linear LDS dest, pre-swizzled global src
__device__ __forceinline__ void stage_tile(char* lds, const char* gtile, int t) {
#pragma unroll
  for (int i = 0; i < 4; ++i) {
    const int L = i * 4096 + t * 16;                 // linear LDS dest (lane-contiguous)
    const int G = L ^ (((L >> 8) & 7) << 4);         // pre-swizzled global source (involution)
    __builtin_amdgcn_global_load_lds(
        (const __attribute__((address_space(1))) void*)(gtile + G),
        (__attribute__((address_space(3))) void*)(lds + L), 16, 0, 0);
  }
}

__global__ __launch_bounds__(256, 4) void kde_kernel(
    const __hip_bfloat16* __restrict__ Hb, const char* __restrict__ Xbc,
    const float* __restrict__ bwp, float* __restrict__ spart) {
  __shared__ char ldsx[2][CH_BYTES];                 // double-buffered X' chunk [64][256B]
  const int t = threadIdx.x;
  const int lane = t & 63, w = t >> 6;
  const int g = lane >> 4, l15 = lane & 15;
  const int rb = blockIdx.x / NSPLIT, sp = blockIdx.x % NSPLIT;
  const int c0 = (sp * NCH) / NSPLIT;
  const int c1 = ((sp + 1) * NCH) / NSPLIT;
  const float bw = bwp[0];
  const float k1 = 1.4426950408889634f / (bw * bw);  // log2(e)/bw^2
  const int rowbase = rb * 128 + w * 32;             // 4 waves x 32 rows = 128 rows/block

  // A fragments: h' rows in registers for the whole kernel (2 rf x 4 ks = 32 VGPR)
  s8v a[2][4];
#pragma unroll
  for (int rf = 0; rf < 2; ++rf)
#pragma unroll
    for (int ks = 0; ks < 4; ++ks) {
      const int row = rowbase + rf * 16 + l15;
      a[rf][ks] = *(const s8v*)(Hb + (size_t)row * KP + ks * 32 + g * 8);
    }

  float sacc[8];                                     // per-lane partial sums (rf x reg)
#pragma unroll
  for (int i = 0; i < 8; ++i) sacc[i] = 0.0f;

  stage_tile(ldsx[0], Xbc + (size_t)c0 * CH_BYTES, t);
  __syncthreads();

  const f4v zero4 = {0.0f, 0.0f, 0.0f, 0.0f};
  for (int ch = c0; ch < c1; ++ch) {
    const int cur = (ch - c0) & 1;
    if (ch + 1 < c1) stage_tile(ldsx[cur ^ 1], Xbc + (size_t)(ch + 1) * CH_BYTES, t);
    const char* lx = ldsx[cur];
#pragma unroll
    for (int cf = 0; cf < 4; ++cf) {                 // 4 col-frags of 16 X-rows
      const int nl = cf * 16 + l15;                  // local X row in chunk
      const int sw = (nl & 7) << 4;                  // read-side XOR swizzle
      const int qb = nl * 256 + g * 16;
      s8v b0 = *(const s8v*)(lx + ((qb) ^ sw));
      s8v b1 = *(const s8v*)(lx + ((qb + 64) ^ sw));
      s8v b2 = *(const s8v*)(lx + ((qb + 128) ^ sw));
      s8v b3 = *(const s8v*)(lx + ((qb + 192) ^ sw));
#pragma unroll
      for (int rf = 0; rf < 2; ++rf) {
        f4v acc = __builtin_amdgcn_mfma_f32_16x16x32_bf16(a[rf][0], b0, zero4, 0, 0, 0);
        acc = __builtin_amdgcn_mfma_f32_16x16x32_bf16(a[rf][1], b1, acc, 0, 0, 0);
        acc = __builtin_amdgcn_mfma_f32_16x16x32_bf16(a[rf][2], b2, acc, 0, 0, 0);
        acc = __builtin_amdgcn_mfma_f32_16x16x32_bf16(a[rf][3], b3, acc, 0, 0, 0);
        // epilogue: acc = -sqdist/2 (aug trick); s += exp2(acc*log2e/bw^2 + 144.27)
#pragma unroll
        for (int reg = 0; reg < 4; ++reg)
          sacc[rf * 4 + reg] += fast_exp2(fmaf(acc[reg], k1, 144.26950408889634f));
      }
    }
    __syncthreads();  // drains prefetch vmcnt + guards LDS reuse (single barrier/chunk)
  }

  // butterfly-reduce the 16 column-lanes; rows live at lane-group g, regs rf x reg
#pragma unroll
  for (int i = 0; i < 8; ++i) {
    float v = sacc[i];
    v += __shfl_xor(v, 1, 64);
    v += __shfl_xor(v, 2, 64);
    v += __shfl_xor(v, 4, 64);
    v += __shfl_xor(v, 8, 64);
    sacc[i] = v;
  }
  if (l15 == 0) {
#pragma unroll
    for (int rf = 0; rf < 2; ++rf)
#pragma unroll
      for (int reg = 0; reg < 4; ++reg) {
        const int row = rowbase + rf * 16 + g * 4 + reg;
        spart[sp * B_ROWS + row] = sacc[rf * 4 + reg];
      }
  }
}

// ---------------- Kernel D: combine partials ----------------
__global__ __launch_bounds__(256) void combine_kernel(
    const float* __restrict__ spart, const float* __restrict__ bwp,
    float* __restrict__ out) {
  const int b = blockIdx.x * 256 + threadIdx.x;
  if (b >= B_ROWS) return;
  float s = 0.f;
#pragma unroll
  for (int sp = 0; sp < NSPLIT; ++sp) s += spart[sp * B_ROWS + b];
  const float bw = bwp[0];
  const float LOG2PI = 1.8378770664093453f;
  const float coeff = -logf((float)N_REF) - 0.5f * LOG2PI * (float)D_PCA
                      - logf(bw) * (float)D_PCA;
  out[b] = logf(s) - 100.0f + coeff;   // undo the +100 exp shift
}

// ---------------- Launch ----------------
extern "C" void kernel_launch(void* const* d_in, const int* in_sizes, int n_in,
                              void* d_out, int out_size, void* d_ws, size_t ws_size,
                              hipStream_t stream) {
  const float* x     = (const float*)d_in[0];   // [4096,512]
  const float* W     = (const float*)d_in[1];   // [100,512]
  const float* bvec  = (const float*)d_in[2];   // [100]
  const float* X     = (const float*)d_in[3];   // [50000,100]
  const float* bwp   = (const float*)d_in[4];   // scalar
  float* out = (float*)d_out;

  char* ws = (char*)d_ws;
  __hip_bfloat16* Hb = (__hip_bfloat16*)ws;                       // 4096*128*2  = 1 MiB
  __hip_bfloat16* Xb = (__hip_bfloat16*)(ws + 1048576);           // 50048*128*2 = 12.22 MiB
  float* spart       = (float*)(ws + 1048576 + 12812288);         // 32*4096*4   = 0.5 MiB

  pca_kernel<<<dim3(B_ROWS / 16), dim3(256), 0, stream>>>(x, W, bvec, Hb);
  xprep_kernel<<<dim3(N_PAD / 16), dim3(256), 0, stream>>>(X, Xb);
  kde_kernel<<<dim3((B_ROWS / 128) * NSPLIT), dim3(256), 0, stream>>>(
      Hb, (const char*)Xb, bwp, spart);
  combine_kernel<<<dim3(B_ROWS / 256), dim3(256), 0, stream>>>(spart, bwp, out);
}